// Round 4
// baseline (1322.669 us; speedup 1.0000x reference)
//
#include <hip/hip_runtime.h>
#include <hip/hip_bf16.h>
#include <stdint.h>

#define DEV static __device__ __forceinline__

typedef unsigned short ushort_t;
typedef __attribute__((ext_vector_type(8))) short bf16x8;   // 8 bf16 = 4 VGPR (MFMA A/B frag)
typedef __attribute__((ext_vector_type(4))) float f32x4;    // MFMA C/D frag

DEV ushort_t f2bf(float f) {
  union { float f; unsigned u; } v; v.f = f;
  unsigned r = v.u + 0x7FFFu + ((v.u >> 16) & 1u);  // RNE
  return (ushort_t)(r >> 16);
}

DEV void async16(const void* g, void* l) {
  __builtin_amdgcn_global_load_lds((const __attribute__((address_space(1))) void*)g,
                                   (__attribute__((address_space(3))) void*)l,
                                   16, 0, 0);
}

// ---------------- elementwise: fp32 -> bf16 weight convert ----------------
__global__ __launch_bounds__(256) void k_cvt(const float* __restrict__ in,
                                             ushort_t* __restrict__ out, int n) {
  int i = (blockIdx.x * 256 + threadIdx.x) * 4;
  if (i >= n) return;
  float4 v = *(const float4*)(in + i);
  ushort4 o = { f2bf(v.x), f2bf(v.y), f2bf(v.z), f2bf(v.w) };
  *(ushort4*)(out + i) = o;
}

// ---------------- RMSNorm (C=2048), one block per row -> bf16 out ----------------
__global__ __launch_bounds__(256) void k_rmsnorm(const float* __restrict__ x,
                                                 const float* __restrict__ w,
                                                 ushort_t* __restrict__ out) {
  __shared__ float red[4];
  int row = blockIdx.x, tid = threadIdx.x;
  const float* xr = x + (size_t)row * 2048 + tid * 8;
  float4 a = *(const float4*)xr;
  float4 b = *(const float4*)(xr + 4);
  float s = a.x*a.x + a.y*a.y + a.z*a.z + a.w*a.w
          + b.x*b.x + b.y*b.y + b.z*b.z + b.w*b.w;
#pragma unroll
  for (int m = 1; m < 64; m <<= 1) s += __shfl_xor(s, m);
  if ((tid & 63) == 0) red[tid >> 6] = s;
  __syncthreads();
  float inv = rsqrtf((red[0] + red[1] + red[2] + red[3]) * (1.0f / 2048.0f) + 1e-5f);
  const float* wp = w + tid * 8;
  ushort_t* op = out + (size_t)row * 2048 + tid * 8;
  ushort4 o0 = { f2bf(a.x*inv*wp[0]), f2bf(a.y*inv*wp[1]), f2bf(a.z*inv*wp[2]), f2bf(a.w*inv*wp[3]) };
  ushort4 o1 = { f2bf(b.x*inv*wp[4]), f2bf(b.y*inv*wp[5]), f2bf(b.z*inv*wp[6]), f2bf(b.w*inv*wp[7]) };
  *(ushort4*)op = o0;
  *(ushort4*)(op + 4) = o1;
}

// ---------------- causal depthwise conv(4) + SiLU + optional RoPE ----------------
// KIND: 0=q(16 heads, rope), 1=k(4 groups, rope), 2=v(4 groups, no rope)
// qkv fp32 [B*T][3072]; out bf16 [B][H][T][128]
template<int KIND>
__global__ __launch_bounds__(256) void k_convrope(const float* __restrict__ qkv,
                                                  const float* __restrict__ cw,
                                                  const float* __restrict__ cs,
                                                  const float* __restrict__ sn,
                                                  ushort_t* __restrict__ outp) {
  const int H = (KIND == 0) ? 16 : 4;
  size_t gid = (size_t)blockIdx.x * 256 + threadIdx.x;
  int i = (int)(gid & 63);
  size_t r = gid >> 6;
  int t = (int)(r & 2047); r >>= 11;
  int h = (int)(r % H);
  int b = (int)(r / H);
  int col0;
  if (KIND == 0)      col0 = (h >> 2) * 768 + (h & 3) * 128;
  else if (KIND == 1) col0 = h * 768 + 512;
  else                col0 = h * 768 + 640;
  const float* w1 = cw + (h * 128 + i) * 4;
  const float* w2 = cw + (h * 128 + 64 + i) * 4;
  float x1 = 0.f, x2 = 0.f;
#pragma unroll
  for (int j = 0; j < 4; j++) {
    int tj = t - 3 + j;
    if (tj >= 0) {
      const float* rp = qkv + ((size_t)b * 2048 + tj) * 3072 + col0 + i;
      x1 += w1[j] * rp[0];
      x2 += w2[j] * rp[64];
    }
  }
  x1 = x1 / (1.f + __expf(-x1));
  x2 = x2 / (1.f + __expf(-x2));
  float o1 = x1, o2 = x2;
  if (KIND != 2) {
    float c = cs[t * 64 + i], s = sn[t * 64 + i];
    o1 = x1 * c - x2 * s;
    o2 = x1 * s + x2 * c;
  }
  ushort_t* o = outp + (((size_t)b * H + h) * 2048 + t) * 128;
  o[i] = f2bf(o1);
  o[i + 64] = f2bf(o2);
}

// ---------------- bf16 GEMM: C[M][N] = A[M][K] * B[N][K]^T (+ epilogue) ----------------
// 128x128 tile, BK=64, 256 threads (4 waves 2x2), mfma_f32_16x16x32_bf16.
// LDS XOR-swizzle (byte ^= (row&7)<<4) realized via pre-swizzled global source
// feeding linear global_load_lds dest; ds_read applies the same swizzle.
#define EPI_F32 0
#define EPI_ADD 1      // outf = acc + Rf   (Rf may alias outf: same-thread RMW)
#define EPI_SILUMUL 2  // outb = bf16( silu(Rb) * acc ),  Rb bf16
#define EPI_BF16 3     // outb = bf16(acc)

template<int EPI>
__global__ __launch_bounds__(256) void k_gemm(const ushort_t* __restrict__ A,
                                              const ushort_t* __restrict__ B,
                                              int M, int N, int K,
                                              const float* __restrict__ Rf,
                                              const ushort_t* __restrict__ Rb,
                                              float* __restrict__ outf,
                                              ushort_t* __restrict__ outb) {
  __shared__ ushort_t As[128 * 64];  // 16KB, 128B rows, swizzled
  __shared__ ushort_t Bs[128 * 64];
  int tid = threadIdx.x, lane = tid & 63, wid = tid >> 6;
  int wr = wid >> 1, wc = wid & 1;
  int nbn = N >> 7;
  int mb = blockIdx.x / nbn, nb = blockIdx.x % nbn;
  const ushort_t* Ab = A + (size_t)mb * 128 * K;
  const ushort_t* Bb = B + (size_t)nb * 128 * K;
  f32x4 acc[4][4] = {};
  for (int k0 = 0; k0 < K; k0 += 64) {
    __syncthreads();
#pragma unroll
    for (int c = 0; c < 4; c++) {
      int o = c * 4096 + tid * 16;            // linear LDS byte offset
      int row = o >> 7;                       // 128B rows
      int src = (o & 127) ^ ((row & 7) << 4); // inverse-swizzled source column-byte
      int ldso = (c * 4096 + wid * 1024) >> 1; // wave-uniform LDS base (elems)
      async16(Ab + (size_t)row * K + k0 + (src >> 1), As + ldso);
      async16(Bb + (size_t)row * K + k0 + (src >> 1), Bs + ldso);
    }
    __syncthreads();
#pragma unroll
    for (int ks = 0; ks < 2; ks++) {
      bf16x8 af[4], bfr[4];
#pragma unroll
      for (int i = 0; i < 4; i++) {
        int ra = wr * 64 + i * 16 + (lane & 15);
        int byt = ks * 64 + ((lane >> 4) << 4);
        af[i] = *(const bf16x8*)((const char*)As + ra * 128 + (byt ^ ((ra & 7) << 4)));
        int rb = wc * 64 + i * 16 + (lane & 15);
        bfr[i] = *(const bf16x8*)((const char*)Bs + rb * 128 + (byt ^ ((rb & 7) << 4)));
      }
#pragma unroll
      for (int i = 0; i < 4; i++)
#pragma unroll
        for (int j = 0; j < 4; j++)
          acc[i][j] = __builtin_amdgcn_mfma_f32_16x16x32_bf16(af[i], bfr[j], acc[i][j], 0, 0, 0);
    }
  }
  int g = lane >> 4, cl = lane & 15;
#pragma unroll
  for (int i = 0; i < 4; i++)
#pragma unroll
    for (int j = 0; j < 4; j++)
#pragma unroll
      for (int rr = 0; rr < 4; rr++) {
        int rowg = mb * 128 + wr * 64 + i * 16 + g * 4 + rr;
        int colg = nb * 128 + wc * 64 + j * 16 + cl;
        size_t idx = (size_t)rowg * N + colg;
        float v = acc[i][j][rr];
        if (EPI == EPI_F32) {
          outf[idx] = v;
        } else if (EPI == EPI_ADD) {
          outf[idx] = v + Rf[idx];
        } else if (EPI == EPI_SILUMUL) {
          float a = __bfloat162float(*(const __hip_bfloat16*)&Rb[idx]);
          outb[idx] = f2bf((a / (1.f + __expf(-a))) * v);
        } else {
          outb[idx] = f2bf(v);
        }
      }
}

// ---------------- flash attention: GQA, causal, 64-row Q tiles ----------------
// Q [B][16][T][128] bf16, K/V [B][4][T][128] bf16, Y [B*T][2048] bf16
__global__ __launch_bounds__(256) void k_attn(const ushort_t* __restrict__ Q,
                                              const ushort_t* __restrict__ Kk,
                                              const ushort_t* __restrict__ V,
                                              ushort_t* __restrict__ Y) {
  __shared__ ushort_t Qs[64 * 128];  // 16KB, 256B rows, swizzled
  __shared__ ushort_t Ks[64 * 128];
  __shared__ ushort_t Vt[128 * 64];  // V^T: [hs][key], 128B rows, swizzled
  __shared__ ushort_t Ps[4 * 16 * 64]; // per-wave P tiles, 128B rows, swizzled
  int qt = 31 - (int)blockIdx.x;     // long blocks dispatch first
  int h = blockIdx.y, b = blockIdx.z, g = h >> 2;
  int tid = threadIdx.x, lane = tid & 63, w = tid >> 6;
  const ushort_t* Qg = Q + (((size_t)b * 16 + h) * 2048 + (size_t)qt * 64) * 128;
  const ushort_t* Kg = Kk + ((size_t)b * 4 + g) * 2048 * 128;
  const ushort_t* Vg = V + ((size_t)b * 4 + g) * 2048 * 128;
#pragma unroll
  for (int c = 0; c < 4; c++) {
    int o = c * 4096 + tid * 16;
    int row = o >> 8;                        // 256B rows
    int src = (o & 255) ^ ((row & 7) << 4);
    async16(Qg + row * 128 + (src >> 1), Qs + ((c * 4096 + w * 1024) >> 1));
  }
  __syncthreads();
  bf16x8 qf[4];  // Q fragments hoisted for the whole kernel
#pragma unroll
  for (int k = 0; k < 4; k++) {
    int row = w * 16 + (lane & 15);
    int byt = k * 64 + ((lane >> 4) << 4);
    qf[k] = *(const bf16x8*)((const char*)Qs + row * 256 + (byt ^ ((row & 7) << 4)));
  }
  f32x4 oacc[8] = {};
  float mrow[4], lrow[4];
#pragma unroll
  for (int rr = 0; rr < 4; rr++) { mrow[rr] = -1e30f; lrow[rr] = 0.f; }
  ushort_t* Pw = Ps + w * 16 * 64;
  for (int kv = 0; kv <= qt; kv++) {
    __syncthreads();  // prev PV done before K/Vt overwrite
    const ushort_t* Kt = Kg + (size_t)kv * 64 * 128;
    const ushort_t* Vtile = Vg + (size_t)kv * 64 * 128;
#pragma unroll
    for (int c = 0; c < 4; c++) {
      int o = c * 4096 + tid * 16;
      int row = o >> 8;
      int src = (o & 255) ^ ((row & 7) << 4);
      async16(Kt + row * 128 + (src >> 1), Ks + ((c * 4096 + w * 1024) >> 1));
    }
    // V transpose into LDS: reads column-strided (L1-served), writes conflict-free
    for (int ii = tid; ii < 8192; ii += 256) {
      int hs = ii >> 6, key = ii & 63;
      ushort_t val = Vtile[key * 128 + hs];
      *(ushort_t*)((char*)Vt + hs * 128 + ((key * 2) ^ ((hs & 7) << 4))) = val;
    }
    __syncthreads();
    // S = Q K^T (16x16 frags; rows=q, cols=keys)
    f32x4 sacc[4] = {};
#pragma unroll
    for (int n = 0; n < 4; n++)
#pragma unroll
      for (int k = 0; k < 4; k++) {
        int row = n * 16 + (lane & 15);
        int byt = k * 64 + ((lane >> 4) << 4);
        bf16x8 kf = *(const bf16x8*)((const char*)Ks + row * 256 + (byt ^ ((row & 7) << 4)));
        sacc[n] = __builtin_amdgcn_mfma_f32_16x16x32_bf16(qf[k], kf, sacc[n], 0, 0, 0);
      }
    const float scl = 0.08838834764831845f;  // 1/sqrt(128)
    float corr[4];
#pragma unroll
    for (int rr = 0; rr < 4; rr++) {
      float mx = -1e30f;
#pragma unroll
      for (int n = 0; n < 4; n++) {
        float s = sacc[n][rr] * scl;
        if (kv == qt) {
          int qrow = w * 16 + (lane >> 4) * 4 + rr;
          int kcol = n * 16 + (lane & 15);
          if (kcol > qrow) s = -1e30f;
        }
        sacc[n][rr] = s;
        mx = fmaxf(mx, s);
      }
      mx = fmaxf(mx, __shfl_xor(mx, 1));
      mx = fmaxf(mx, __shfl_xor(mx, 2));
      mx = fmaxf(mx, __shfl_xor(mx, 4));
      mx = fmaxf(mx, __shfl_xor(mx, 8));
      float mnew = fmaxf(mrow[rr], mx);
      float co = __expf(mrow[rr] - mnew);
      mrow[rr] = mnew;
      corr[rr] = co;
      float ps = 0.f;
#pragma unroll
      for (int n = 0; n < 4; n++) {
        float p = __expf(sacc[n][rr] - mnew);
        sacc[n][rr] = p;
        ps += p;
      }
      ps += __shfl_xor(ps, 1);
      ps += __shfl_xor(ps, 2);
      ps += __shfl_xor(ps, 4);
      ps += __shfl_xor(ps, 8);
      lrow[rr] = lrow[rr] * co + ps;
    }
#pragma unroll
    for (int no = 0; no < 8; no++)
#pragma unroll
      for (int rr = 0; rr < 4; rr++) oacc[no][rr] *= corr[rr];
    // P -> bf16 -> per-wave LDS (A-frag layout source)
#pragma unroll
    for (int n = 0; n < 4; n++)
#pragma unroll
      for (int rr = 0; rr < 4; rr++) {
        int prow = (lane >> 4) * 4 + rr;
        int pbyt = (n * 16 + (lane & 15)) * 2;
        *(ushort_t*)((char*)Pw + prow * 128 + (pbyt ^ ((prow & 7) << 4))) = f2bf(sacc[n][rr]);
      }
    // same-wave LDS write->read: force completion + pin order (rule #18)
    asm volatile("s_waitcnt lgkmcnt(0)" ::: "memory");
    __builtin_amdgcn_sched_barrier(0);
    // O += P V
#pragma unroll
    for (int ks = 0; ks < 2; ks++) {
      int prow = lane & 15;
      int pbyt = ks * 64 + ((lane >> 4) << 4);
      bf16x8 pf = *(const bf16x8*)((const char*)Pw + prow * 128 + (pbyt ^ ((prow & 7) << 4)));
#pragma unroll
      for (int no = 0; no < 8; no++) {
        int vrow = no * 16 + (lane & 15);
        bf16x8 vf = *(const bf16x8*)((const char*)Vt + vrow * 128 + (pbyt ^ ((vrow & 7) << 4)));
        oacc[no] = __builtin_amdgcn_mfma_f32_16x16x32_bf16(pf, vf, oacc[no], 0, 0, 0);
      }
    }
  }
  float inv[4];
#pragma unroll
  for (int rr = 0; rr < 4; rr++) inv[rr] = 1.f / lrow[rr];
#pragma unroll
  for (int no = 0; no < 8; no++)
#pragma unroll
    for (int rr = 0; rr < 4; rr++) {
      int t = qt * 64 + w * 16 + (lane >> 4) * 4 + rr;
      int col = no * 16 + (lane & 15);
      Y[((size_t)b * 2048 + t) * 2048 + h * 128 + col] = f2bf(oacc[no][rr] * inv[rr]);
    }
}

// ---------------- launch ----------------
// Workspace budget (203.4 MB total, lifetime-aliased):
//   weights (persistent): attn 12.6 + proj 8.4 + fc1 23.1 + fc2 23.1 + mlp 23.1 = 90.2 MB
//   n_bf 16.8 MB (rmsnorm1 out -> qkv gemm; later rmsnorm2 out -> fc1/fc2)
//   bufA 50.3 MB: qkv_f fp32 (dead after convrope) -> a_bf bf16 [4096][5632] (46.1)
//   bufB 46.1 MB: q(16.8)+k(4.2)+v(4.2)+y(16.8)=42.0 (dead after proj gemm) -> h_bf (46.1)
//   x1 (fp32 residual) lives in d_out (proj writes it; rmsnorm2 + final gemm read it;
//   final gemm does out[idx] = acc + out[idx], same-thread RMW).
extern "C" void kernel_launch(void* const* d_in, const int* in_sizes, int n_in,
                              void* d_out, int out_size, void* d_ws, size_t ws_size,
                              hipStream_t stream) {
  (void)in_sizes; (void)n_in; (void)out_size; (void)ws_size;
  const float* x     = (const float*)d_in[0];
  const float* cosp  = (const float*)d_in[1];
  const float* sinp  = (const float*)d_in[2];
  const float* n1w   = (const float*)d_in[3];
  const float* attnw = (const float*)d_in[4];
  const float* projw = (const float*)d_in[5];
  const float* qcw   = (const float*)d_in[6];
  const float* kcw   = (const float*)d_in[7];
  const float* vcw   = (const float*)d_in[8];
  const float* n2w   = (const float*)d_in[9];
  const float* fc1w  = (const float*)d_in[10];
  const float* fc2w  = (const float*)d_in[11];
  const float* mlpw  = (const float*)d_in[12];
  float* outp = (float*)d_out;

  char* p = (char*)d_ws;
  ushort_t* attn_bf = (ushort_t*)p; p += (size_t)3072 * 2048 * 2;
  ushort_t* proj_bf = (ushort_t*)p; p += (size_t)2048 * 2048 * 2;
  ushort_t* fc1_bf  = (ushort_t*)p; p += (size_t)5632 * 2048 * 2;
  ushort_t* fc2_bf  = (ushort_t*)p; p += (size_t)5632 * 2048 * 2;
  ushort_t* mlp_bf  = (ushort_t*)p; p += (size_t)2048 * 5632 * 2;
  ushort_t* n_bf    = (ushort_t*)p; p += (size_t)4096 * 2048 * 2;
  char* bufA = p; p += (size_t)4096 * 3072 * 4;      // 50.3 MB
  char* bufB = p; p += (size_t)4096 * 5632 * 2;      // 46.1 MB

  float*    qkv_f = (float*)bufA;                    // phase A-B
  ushort_t* a_bf  = (ushort_t*)bufA;                 // phase F-G (46.1 <= 50.3)
  ushort_t* q_bf  = (ushort_t*)bufB;                               // 16.8 MB
  ushort_t* k_bf  = (ushort_t*)(bufB + (size_t)16777216);          //  4.2 MB
  ushort_t* v_bf  = (ushort_t*)(bufB + (size_t)20971520);          //  4.2 MB
  ushort_t* y_bf  = (ushort_t*)(bufB + (size_t)25165824);          // 16.8 MB
  ushort_t* h_bf  = (ushort_t*)bufB;                 // phase G-H (46.1 == 46.1)

  k_cvt<<<3072 * 2048 / 1024, 256, 0, stream>>>(attnw, attn_bf, 3072 * 2048);
  k_cvt<<<2048 * 2048 / 1024, 256, 0, stream>>>(projw, proj_bf, 2048 * 2048);
  k_cvt<<<5632 * 2048 / 1024, 256, 0, stream>>>(fc1w, fc1_bf, 5632 * 2048);
  k_cvt<<<5632 * 2048 / 1024, 256, 0, stream>>>(fc2w, fc2_bf, 5632 * 2048);
  k_cvt<<<2048 * 5632 / 1024, 256, 0, stream>>>(mlpw, mlp_bf, 2048 * 5632);

  k_rmsnorm<<<4096, 256, 0, stream>>>(x, n1w, n_bf);

  k_gemm<EPI_F32><<<32 * 24, 256, 0, stream>>>(n_bf, attn_bf, 4096, 3072, 2048,
                                               nullptr, nullptr, qkv_f, nullptr);

  k_convrope<0><<<16384, 256, 0, stream>>>(qkv_f, qcw, cosp, sinp, q_bf);
  k_convrope<1><<<4096, 256, 0, stream>>>(qkv_f, kcw, cosp, sinp, k_bf);
  k_convrope<2><<<4096, 256, 0, stream>>>(qkv_f, vcw, cosp, sinp, v_bf);

  k_attn<<<dim3(32, 16, 2), 256, 0, stream>>>(q_bf, k_bf, v_bf, y_bf);

  k_gemm<EPI_ADD><<<32 * 16, 256, 0, stream>>>(y_bf, proj_bf, 4096, 2048, 2048,
                                               x, nullptr, outp, nullptr);

  k_rmsnorm<<<4096, 256, 0, stream>>>(outp, n2w, n_bf);

  k_gemm<EPI_BF16><<<32 * 44, 256, 0, stream>>>(n_bf, fc1_bf, 4096, 5632, 2048,
                                                nullptr, nullptr, nullptr, a_bf);
  k_gemm<EPI_SILUMUL><<<32 * 44, 256, 0, stream>>>(n_bf, fc2_bf, 4096, 5632, 2048,
                                                   nullptr, a_bf, nullptr, h_bf);
  k_gemm<EPI_ADD><<<32 * 16, 256, 0, stream>>>(h_bf, mlp_bf, 4096, 2048, 5632,
                                               outp, nullptr, outp, nullptr);
}

// Round 5
// 970.304 us; speedup vs baseline: 1.3631x; 1.3631x over previous
//
#include <hip/hip_runtime.h>
#include <hip/hip_bf16.h>
#include <stdint.h>

#define DEV static __device__ __forceinline__

typedef unsigned short ushort_t;
typedef __attribute__((ext_vector_type(8))) short bf16x8;   // 8 bf16 = 4 VGPR (MFMA A/B frag)
typedef __attribute__((ext_vector_type(8))) short short8;
typedef __attribute__((ext_vector_type(4))) float f32x4;    // MFMA C/D frag

DEV ushort_t f2bf(float f) {
  union { float f; unsigned u; } v; v.f = f;
  unsigned r = v.u + 0x7FFFu + ((v.u >> 16) & 1u);  // RNE
  return (ushort_t)(r >> 16);
}

DEV void async16(const void* g, void* l) {
  __builtin_amdgcn_global_load_lds((const __attribute__((address_space(1))) void*)g,
                                   (__attribute__((address_space(3))) void*)l,
                                   16, 0, 0);
}

// ---------------- elementwise: fp32 -> bf16 weight convert ----------------
__global__ __launch_bounds__(256) void k_cvt(const float* __restrict__ in,
                                             ushort_t* __restrict__ out, int n) {
  int i = (blockIdx.x * 256 + threadIdx.x) * 4;
  if (i >= n) return;
  float4 v = *(const float4*)(in + i);
  ushort4 o = { f2bf(v.x), f2bf(v.y), f2bf(v.z), f2bf(v.w) };
  *(ushort4*)(out + i) = o;
}

// ---------------- RMSNorm (C=2048), one block per row -> bf16 out ----------------
__global__ __launch_bounds__(256) void k_rmsnorm(const float* __restrict__ x,
                                                 const float* __restrict__ w,
                                                 ushort_t* __restrict__ out) {
  __shared__ float red[4];
  int row = blockIdx.x, tid = threadIdx.x;
  const float* xr = x + (size_t)row * 2048 + tid * 8;
  float4 a = *(const float4*)xr;
  float4 b = *(const float4*)(xr + 4);
  float s = a.x*a.x + a.y*a.y + a.z*a.z + a.w*a.w
          + b.x*b.x + b.y*b.y + b.z*b.z + b.w*b.w;
#pragma unroll
  for (int m = 1; m < 64; m <<= 1) s += __shfl_xor(s, m);
  if ((tid & 63) == 0) red[tid >> 6] = s;
  __syncthreads();
  float inv = rsqrtf((red[0] + red[1] + red[2] + red[3]) * (1.0f / 2048.0f) + 1e-5f);
  const float* wp = w + tid * 8;
  ushort_t* op = out + (size_t)row * 2048 + tid * 8;
  ushort4 o0 = { f2bf(a.x*inv*wp[0]), f2bf(a.y*inv*wp[1]), f2bf(a.z*inv*wp[2]), f2bf(a.w*inv*wp[3]) };
  ushort4 o1 = { f2bf(b.x*inv*wp[4]), f2bf(b.y*inv*wp[5]), f2bf(b.z*inv*wp[6]), f2bf(b.w*inv*wp[7]) };
  *(ushort4*)op = o0;
  *(ushort4*)(op + 4) = o1;
}

// ---------------- causal depthwise conv(4) + SiLU + optional RoPE ----------------
// KIND: 0=q(16 heads, rope), 1=k(4 groups, rope), 2=v(4 groups, no rope)
// qkv fp32 [B*T][3072]; out bf16 [B][H][T][128]
template<int KIND>
__global__ __launch_bounds__(256) void k_convrope(const float* __restrict__ qkv,
                                                  const float* __restrict__ cw,
                                                  const float* __restrict__ cs,
                                                  const float* __restrict__ sn,
                                                  ushort_t* __restrict__ outp) {
  const int H = (KIND == 0) ? 16 : 4;
  size_t gid = (size_t)blockIdx.x * 256 + threadIdx.x;
  int i = (int)(gid & 63);
  size_t r = gid >> 6;
  int t = (int)(r & 2047); r >>= 11;
  int h = (int)(r % H);
  int b = (int)(r / H);
  int col0;
  if (KIND == 0)      col0 = (h >> 2) * 768 + (h & 3) * 128;
  else if (KIND == 1) col0 = h * 768 + 512;
  else                col0 = h * 768 + 640;
  const float* w1 = cw + (h * 128 + i) * 4;
  const float* w2 = cw + (h * 128 + 64 + i) * 4;
  float x1 = 0.f, x2 = 0.f;
#pragma unroll
  for (int j = 0; j < 4; j++) {
    int tj = t - 3 + j;
    if (tj >= 0) {
      const float* rp = qkv + ((size_t)b * 2048 + tj) * 3072 + col0 + i;
      x1 += w1[j] * rp[0];
      x2 += w2[j] * rp[64];
    }
  }
  x1 = x1 / (1.f + __expf(-x1));
  x2 = x2 / (1.f + __expf(-x2));
  float o1 = x1, o2 = x2;
  if (KIND != 2) {
    float c = cs[t * 64 + i], s = sn[t * 64 + i];
    o1 = x1 * c - x2 * s;
    o2 = x1 * s + x2 * c;
  }
  ushort_t* o = outp + (((size_t)b * H + h) * 2048 + t) * 128;
  o[i] = f2bf(o1);
  o[i + 64] = f2bf(o2);
}

// ---------------- V transpose: [B*4][2048][128] -> [B*4][128][2048] ----------------
// 64x64 LDS tiles; coalesced loads + coalesced-enough stores. ~8.4MB r+w total.
__global__ __launch_bounds__(256) void k_transpose(const ushort_t* __restrict__ v,
                                                   ushort_t* __restrict__ vt) {
  __shared__ ushort_t tile[64][72];   // +8 pad vs 64 (keeps 16B align: 144B rows)
  int bg = blockIdx.z;
  int t0 = blockIdx.x * 64;
  int d0 = blockIdx.y * 64;
  int r = threadIdx.x >> 2, c0 = (threadIdx.x & 3) * 16;
  const ushort_t* src = v + ((size_t)bg * 2048 + t0) * 128 + d0 + (size_t)r * 128 + c0;
  *(short8*)&tile[r][c0]     = *(const short8*)src;
  *(short8*)&tile[r][c0 + 8] = *(const short8*)(src + 8);
  __syncthreads();
  short8 a, b2;
#pragma unroll
  for (int j = 0; j < 8; j++) {
    a[j]  = (short)tile[c0 + j][r];
    b2[j] = (short)tile[c0 + 8 + j][r];
  }
  ushort_t* dst = vt + ((size_t)bg * 128 + d0 + r) * 2048 + t0 + c0;
  *(short8*)dst       = a;
  *(short8*)(dst + 8) = b2;
}

// ---------------- bf16 GEMM: C[M][N] = A[M][K] * B[N][K]^T (+ epilogue) ----------------
// 128x128 tile, BK=64, 256 threads (4 waves 2x2), mfma_f32_16x16x32_bf16.
// LDS XOR-swizzle (byte ^= (row&7)<<4) realized via pre-swizzled global source
// feeding linear global_load_lds dest; ds_read applies the same swizzle.
#define EPI_F32 0
#define EPI_ADD 1      // outf = acc + Rf   (Rf may alias outf: same-thread RMW)
#define EPI_SILUMUL 2  // outb = bf16( silu(Rb) * acc ),  Rb bf16
#define EPI_BF16 3     // outb = bf16(acc)

template<int EPI>
__global__ __launch_bounds__(256) void k_gemm(const ushort_t* __restrict__ A,
                                              const ushort_t* __restrict__ B,
                                              int M, int N, int K,
                                              const float* __restrict__ Rf,
                                              const ushort_t* __restrict__ Rb,
                                              float* __restrict__ outf,
                                              ushort_t* __restrict__ outb) {
  __shared__ ushort_t As[128 * 64];  // 16KB, 128B rows, swizzled
  __shared__ ushort_t Bs[128 * 64];
  int tid = threadIdx.x, lane = tid & 63, wid = tid >> 6;
  int wr = wid >> 1, wc = wid & 1;
  int nbn = N >> 7;
  int mb = blockIdx.x / nbn, nb = blockIdx.x % nbn;
  const ushort_t* Ab = A + (size_t)mb * 128 * K;
  const ushort_t* Bb = B + (size_t)nb * 128 * K;
  f32x4 acc[4][4] = {};
  for (int k0 = 0; k0 < K; k0 += 64) {
    __syncthreads();
#pragma unroll
    for (int c = 0; c < 4; c++) {
      int o = c * 4096 + tid * 16;            // linear LDS byte offset
      int row = o >> 7;                       // 128B rows
      int src = (o & 127) ^ ((row & 7) << 4); // inverse-swizzled source column-byte
      int ldso = (c * 4096 + wid * 1024) >> 1; // wave-uniform LDS base (elems)
      async16(Ab + (size_t)row * K + k0 + (src >> 1), As + ldso);
      async16(Bb + (size_t)row * K + k0 + (src >> 1), Bs + ldso);
    }
    __syncthreads();
#pragma unroll
    for (int ks = 0; ks < 2; ks++) {
      bf16x8 af[4], bfr[4];
#pragma unroll
      for (int i = 0; i < 4; i++) {
        int ra = wr * 64 + i * 16 + (lane & 15);
        int byt = ks * 64 + ((lane >> 4) << 4);
        af[i] = *(const bf16x8*)((const char*)As + ra * 128 + (byt ^ ((ra & 7) << 4)));
        int rb = wc * 64 + i * 16 + (lane & 15);
        bfr[i] = *(const bf16x8*)((const char*)Bs + rb * 128 + (byt ^ ((rb & 7) << 4)));
      }
#pragma unroll
      for (int i = 0; i < 4; i++)
#pragma unroll
        for (int j = 0; j < 4; j++)
          acc[i][j] = __builtin_amdgcn_mfma_f32_16x16x32_bf16(af[i], bfr[j], acc[i][j], 0, 0, 0);
    }
  }
  int g = lane >> 4, cl = lane & 15;
#pragma unroll
  for (int i = 0; i < 4; i++)
#pragma unroll
    for (int j = 0; j < 4; j++)
#pragma unroll
      for (int rr = 0; rr < 4; rr++) {
        int rowg = mb * 128 + wr * 64 + i * 16 + g * 4 + rr;
        int colg = nb * 128 + wc * 64 + j * 16 + cl;
        size_t idx = (size_t)rowg * N + colg;
        float v = acc[i][j][rr];
        if (EPI == EPI_F32) {
          outf[idx] = v;
        } else if (EPI == EPI_ADD) {
          outf[idx] = v + Rf[idx];
        } else if (EPI == EPI_SILUMUL) {
          float a = __bfloat162float(*(const __hip_bfloat16*)&Rb[idx]);
          outb[idx] = f2bf((a / (1.f + __expf(-a))) * v);
        } else {
          outb[idx] = f2bf(v);
        }
      }
}

// ---------------- flash attention: GQA, causal, 64-row Q tiles ----------------
// Q [B][16][T][128] bf16, K [B][4][T][128] bf16, VT [B][4][128][T] bf16
// LDS 40KB -> 4 blocks/CU. Q staged through Ks (dead after qf hoist).
__global__ __launch_bounds__(256) void k_attn(const ushort_t* __restrict__ Q,
                                              const ushort_t* __restrict__ Kk,
                                              const ushort_t* __restrict__ VT,
                                              ushort_t* __restrict__ Y) {
  __shared__ ushort_t Ks[64 * 128];   // 16KB: Q (prologue) then K tiles; 256B rows swz
  __shared__ ushort_t Vt[128 * 64];   // 16KB: V^T tile [d][key]; 128B rows swz
  __shared__ ushort_t Ps[4 * 16 * 64];// 8KB per-wave P tiles
  int qt = 31 - (int)blockIdx.x;      // long blocks dispatch first
  int h = blockIdx.y, b = blockIdx.z, g = h >> 2;
  int tid = threadIdx.x, lane = tid & 63, w = tid >> 6;
  const ushort_t* Qg  = Q  + (((size_t)b * 16 + h) * 2048 + (size_t)qt * 64) * 128;
  const ushort_t* Kg  = Kk + ((size_t)b * 4 + g) * 2048 * 128;
  const ushort_t* VTg = VT + ((size_t)b * 4 + g) * 128 * 2048;
  // ---- prologue: stage Q tile into Ks, hoist fragments ----
#pragma unroll
  for (int c = 0; c < 4; c++) {
    int o = c * 4096 + tid * 16;
    int row = o >> 8;                        // 256B rows
    int src = (o & 255) ^ ((row & 7) << 4);
    async16(Qg + row * 128 + (src >> 1), Ks + ((c * 4096 + w * 1024) >> 1));
  }
  __syncthreads();
  bf16x8 qf[4];
#pragma unroll
  for (int k = 0; k < 4; k++) {
    int row = w * 16 + (lane & 15);
    int byt = k * 64 + ((lane >> 4) << 4);
    qf[k] = *(const bf16x8*)((const char*)Ks + row * 256 + (byt ^ ((row & 7) << 4)));
  }
  f32x4 oacc[8] = {};
  float mrow[4], lrow[4];
#pragma unroll
  for (int rr = 0; rr < 4; rr++) { mrow[rr] = -1e30f; lrow[rr] = 0.f; }
  ushort_t* Pw = Ps + w * 16 * 64;
  for (int kv = 0; kv <= qt; kv++) {
    __syncthreads();  // prev-iter LDS reads done (iter0: qf reads done)
    const ushort_t* Kt = Kg + (size_t)kv * 64 * 128;
#pragma unroll
    for (int c = 0; c < 4; c++) {            // K tile: 64 rows x 256B
      int o = c * 4096 + tid * 16;
      int row = o >> 8;
      int src = (o & 255) ^ ((row & 7) << 4);
      async16(Kt + row * 128 + (src >> 1), Ks + ((c * 4096 + w * 1024) >> 1));
    }
#pragma unroll
    for (int c = 0; c < 4; c++) {            // V^T tile: 128 rows x 128B
      int o = c * 4096 + tid * 16;
      int row = o >> 7;
      int src = (o & 127) ^ ((row & 7) << 4);
      async16(VTg + (size_t)row * 2048 + kv * 64 + (src >> 1), Vt + ((c * 4096 + w * 1024) >> 1));
    }
    __syncthreads();
    // S = Q K^T
    f32x4 sacc[4] = {};
#pragma unroll
    for (int n = 0; n < 4; n++)
#pragma unroll
      for (int k = 0; k < 4; k++) {
        int row = n * 16 + (lane & 15);
        int byt = k * 64 + ((lane >> 4) << 4);
        bf16x8 kf = *(const bf16x8*)((const char*)Ks + row * 256 + (byt ^ ((row & 7) << 4)));
        sacc[n] = __builtin_amdgcn_mfma_f32_16x16x32_bf16(qf[k], kf, sacc[n], 0, 0, 0);
      }
    const float scl = 0.08838834764831845f;  // 1/sqrt(128)
    float corr[4];
#pragma unroll
    for (int rr = 0; rr < 4; rr++) {
      float mx = -1e30f;
#pragma unroll
      for (int n = 0; n < 4; n++) {
        float s = sacc[n][rr] * scl;
        if (kv == qt) {
          int qrow = w * 16 + (lane >> 4) * 4 + rr;
          int kcol = n * 16 + (lane & 15);
          if (kcol > qrow) s = -1e30f;
        }
        sacc[n][rr] = s;
        mx = fmaxf(mx, s);
      }
      mx = fmaxf(mx, __shfl_xor(mx, 1));
      mx = fmaxf(mx, __shfl_xor(mx, 2));
      mx = fmaxf(mx, __shfl_xor(mx, 4));
      mx = fmaxf(mx, __shfl_xor(mx, 8));
      float mnew = fmaxf(mrow[rr], mx);
      float co = __expf(mrow[rr] - mnew);   // uniform across the 16-lane group
      mrow[rr] = mnew;
      corr[rr] = co;
      float ps = 0.f;                        // per-lane partial; reduced once at end
#pragma unroll
      for (int n = 0; n < 4; n++) {
        float p = __expf(sacc[n][rr] - mnew);
        sacc[n][rr] = p;
        ps += p;
      }
      lrow[rr] = lrow[rr] * co + ps;
    }
#pragma unroll
    for (int no = 0; no < 8; no++)
#pragma unroll
      for (int rr = 0; rr < 4; rr++) oacc[no][rr] *= corr[rr];
    // P -> bf16 -> per-wave LDS (A-frag layout source)
#pragma unroll
    for (int n = 0; n < 4; n++)
#pragma unroll
      for (int rr = 0; rr < 4; rr++) {
        int prow = (lane >> 4) * 4 + rr;
        int pbyt = (n * 16 + (lane & 15)) * 2;
        *(ushort_t*)((char*)Pw + prow * 128 + (pbyt ^ ((prow & 7) << 4))) = f2bf(sacc[n][rr]);
      }
    // same-wave LDS write->read: force completion + pin order (rule #18)
    asm volatile("s_waitcnt lgkmcnt(0)" ::: "memory");
    __builtin_amdgcn_sched_barrier(0);
    // O += P V
#pragma unroll
    for (int ks = 0; ks < 2; ks++) {
      int prow = lane & 15;
      int pbyt = ks * 64 + ((lane >> 4) << 4);
      bf16x8 pf = *(const bf16x8*)((const char*)Pw + prow * 128 + (pbyt ^ ((prow & 7) << 4)));
#pragma unroll
      for (int no = 0; no < 8; no++) {
        int vrow = no * 16 + (lane & 15);
        bf16x8 vf = *(const bf16x8*)((const char*)Vt + vrow * 128 + (pbyt ^ ((vrow & 7) << 4)));
        oacc[no] = __builtin_amdgcn_mfma_f32_16x16x32_bf16(pf, vf, oacc[no], 0, 0, 0);
      }
    }
  }
  float inv[4];
#pragma unroll
  for (int rr = 0; rr < 4; rr++) {
    float s = lrow[rr];
    s += __shfl_xor(s, 1);
    s += __shfl_xor(s, 2);
    s += __shfl_xor(s, 4);
    s += __shfl_xor(s, 8);
    inv[rr] = 1.f / s;
  }
#pragma unroll
  for (int no = 0; no < 8; no++)
#pragma unroll
    for (int rr = 0; rr < 4; rr++) {
      int t = qt * 64 + w * 16 + (lane >> 4) * 4 + rr;
      int col = no * 16 + (lane & 15);
      Y[((size_t)b * 2048 + t) * 2048 + h * 128 + col] = f2bf(oacc[no][rr] * inv[rr]);
    }
}

// ---------------- launch ----------------
// Workspace (lifetime-aliased, ~203 MB):
//   weights persistent 90.2 MB | n_bf 16.8 MB
//   bufA 50.3 MB: qkv_f fp32 (dead after convrope) -> vt_bf 4.2MB (dead after attn) -> a_bf 46.1MB
//   bufB 46.1 MB: q+k+v+y (dead after proj gemm) -> h_bf 46.1MB
//   x1 residual lives in d_out.
extern "C" void kernel_launch(void* const* d_in, const int* in_sizes, int n_in,
                              void* d_out, int out_size, void* d_ws, size_t ws_size,
                              hipStream_t stream) {
  (void)in_sizes; (void)n_in; (void)out_size; (void)ws_size;
  const float* x     = (const float*)d_in[0];
  const float* cosp  = (const float*)d_in[1];
  const float* sinp  = (const float*)d_in[2];
  const float* n1w   = (const float*)d_in[3];
  const float* attnw = (const float*)d_in[4];
  const float* projw = (const float*)d_in[5];
  const float* qcw   = (const float*)d_in[6];
  const float* kcw   = (const float*)d_in[7];
  const float* vcw   = (const float*)d_in[8];
  const float* n2w   = (const float*)d_in[9];
  const float* fc1w  = (const float*)d_in[10];
  const float* fc2w  = (const float*)d_in[11];
  const float* mlpw  = (const float*)d_in[12];
  float* outp = (float*)d_out;

  char* p = (char*)d_ws;
  ushort_t* attn_bf = (ushort_t*)p; p += (size_t)3072 * 2048 * 2;
  ushort_t* proj_bf = (ushort_t*)p; p += (size_t)2048 * 2048 * 2;
  ushort_t* fc1_bf  = (ushort_t*)p; p += (size_t)5632 * 2048 * 2;
  ushort_t* fc2_bf  = (ushort_t*)p; p += (size_t)5632 * 2048 * 2;
  ushort_t* mlp_bf  = (ushort_t*)p; p += (size_t)2048 * 5632 * 2;
  ushort_t* n_bf    = (ushort_t*)p; p += (size_t)4096 * 2048 * 2;
  char* bufA = p; p += (size_t)4096 * 3072 * 4;      // 50.3 MB
  char* bufB = p; p += (size_t)4096 * 5632 * 2;      // 46.1 MB

  float*    qkv_f = (float*)bufA;                    // phase A-B
  ushort_t* vt_bf = (ushort_t*)bufA;                 // phase C (V^T, 4.2 MB)
  ushort_t* a_bf  = (ushort_t*)bufA;                 // phase F-G (46.1 <= 50.3)
  ushort_t* q_bf  = (ushort_t*)bufB;                               // 16.8 MB
  ushort_t* k_bf  = (ushort_t*)(bufB + (size_t)16777216);          //  4.2 MB
  ushort_t* v_bf  = (ushort_t*)(bufB + (size_t)20971520);          //  4.2 MB
  ushort_t* y_bf  = (ushort_t*)(bufB + (size_t)25165824);          // 16.8 MB
  ushort_t* h_bf  = (ushort_t*)bufB;                 // phase G-H (46.1 == 46.1)

  k_cvt<<<3072 * 2048 / 1024, 256, 0, stream>>>(attnw, attn_bf, 3072 * 2048);
  k_cvt<<<2048 * 2048 / 1024, 256, 0, stream>>>(projw, proj_bf, 2048 * 2048);
  k_cvt<<<5632 * 2048 / 1024, 256, 0, stream>>>(fc1w, fc1_bf, 5632 * 2048);
  k_cvt<<<5632 * 2048 / 1024, 256, 0, stream>>>(fc2w, fc2_bf, 5632 * 2048);
  k_cvt<<<2048 * 5632 / 1024, 256, 0, stream>>>(mlpw, mlp_bf, 2048 * 5632);

  k_rmsnorm<<<4096, 256, 0, stream>>>(x, n1w, n_bf);

  k_gemm<EPI_F32><<<32 * 24, 256, 0, stream>>>(n_bf, attn_bf, 4096, 3072, 2048,
                                               nullptr, nullptr, qkv_f, nullptr);

  k_convrope<0><<<16384, 256, 0, stream>>>(qkv_f, qcw, cosp, sinp, q_bf);
  k_convrope<1><<<4096, 256, 0, stream>>>(qkv_f, kcw, cosp, sinp, k_bf);
  k_convrope<2><<<4096, 256, 0, stream>>>(qkv_f, vcw, cosp, sinp, v_bf);

  k_transpose<<<dim3(32, 2, 8), 256, 0, stream>>>(v_bf, vt_bf);

  k_attn<<<dim3(32, 16, 2), 256, 0, stream>>>(q_bf, k_bf, vt_bf, y_bf);

  k_gemm<EPI_ADD><<<32 * 16, 256, 0, stream>>>(y_bf, proj_bf, 4096, 2048, 2048,
                                               x, nullptr, outp, nullptr);

  k_rmsnorm<<<4096, 256, 0, stream>>>(outp, n2w, n_bf);

  k_gemm<EPI_BF16><<<32 * 44, 256, 0, stream>>>(n_bf, fc1_bf, 4096, 5632, 2048,
                                                nullptr, nullptr, nullptr, a_bf);
  k_gemm<EPI_SILUMUL><<<32 * 44, 256, 0, stream>>>(n_bf, fc2_bf, 4096, 5632, 2048,
                                                   nullptr, a_bf, nullptr, h_bf);
  k_gemm<EPI_ADD><<<32 * 16, 256, 0, stream>>>(h_bf, mlp_bf, 4096, 2048, 5632,
                                               outp, nullptr, outp, nullptr);
}